// Round 2
// baseline (75.514 us; speedup 1.0000x reference)
//
#include <hip/hip_runtime.h>

// ---------------------------------------------------------------------------
// KAN conv, fully fused (round 7):
//   out[b,o,oh,ow] = sum_{di,dj,j,c} feat_j(x[b,c,oh+di-1,ow+dj-1]) * Wb[o,pos,j,c] + bias[o]
//   feat_0 = silu(t), feat_1..8 = cubic B-spline bases (t=0 outside image)
//
// Round-7 changes vs round-6 (theory: Phase B og-replicated DS reads + barrier
// convoys at 1 block/CU own the remaining kernel-side time):
//  * Phase B: wave = O32 (og x2) x kq x8.  Per step: 2 Wb frags + SAME 2
//    a-frags -> 4 MFMAs.  Halves ds_read_b128 count (640 -> 320 per block).
//  * Phase A: stage all 3 x rows -> LDS before ONE barrier (8 -> 4 barriers
//    total); feature compute for all rows barrier-free afterwards.
//  * Phase C: uniform — ALL 16 waves write partials to LDS, then all 1024
//    threads reduce 2 outputs each (8 partial groups), float2 stores.
// Workspace use: Wb only (331,776 B).  Poison fill (~41us) is harness floor.
// ---------------------------------------------------------------------------

typedef __attribute__((ext_vector_type(8))) short v8s;
typedef __attribute__((ext_vector_type(4))) float v4f;
typedef __attribute__((ext_vector_type(4))) int   v4i;
typedef unsigned short ushort_t;

#define CELL_STRIDE 296                  // ushort elems/cell = 592 B (16B-aligned)
#define ROW_STRIDE  (34 * CELL_STRIDE)   // 10,064 elems = 20,128 B
#define FEAT_BYTES  (3 * ROW_STRIDE * 2) // 60,384 B
#define XS_OFF      FEAT_BYTES           // xs: 3 x 1056 fp32 = 12,672 B
#define DUMP_OFF    (XS_OFF + 12672)     // 128 B sink
#define SMEM_BYTES  (DUMP_OFF + 128)     // 73,184 B  (red needs 67,584 B <= this)

__device__ __forceinline__ unsigned short f2bf(float v) {
  union { float f; unsigned int u; } w; w.f = v;
  unsigned int r = w.u + 0x7FFFu + ((w.u >> 16) & 1u);   // RNE
  return (unsigned short)(r >> 16);
}

// ---------------------------------------------------------------------------
// Kernel 1: fold weights  Wb[o][pos][j][c] = (j==0 ? sb : ssp*coef[j-1]), bf16
// Block-per-o LDS transpose; coalesced loads and stores.  (unchanged)
// ---------------------------------------------------------------------------
__global__ __launch_bounds__(256) void kan_prep(const float* __restrict__ coef,
                                                const float* __restrict__ sb,
                                                const float* __restrict__ ssp,
                                                ushort_t* __restrict__ Wb) {
  __shared__ ushort_t row_[2592];
  const int o   = blockIdx.x;
  const int tid = threadIdx.x;
  const float* cf   = coef + o * 2304;   // [c][pos][m] = 32*9*8
  const float* sspo = ssp  + o * 288;    // [c][pos]
  const float* sbo  = sb   + o * 288;

#pragma unroll
  for (int k = 0; k < 9; ++k) {
    int l   = k * 256 + tid;             // 0..2303, linear in coef
    int c   = l / 72;
    int rem = l - c * 72;
    int pos = rem >> 3;
    int m   = rem & 7;
    float v = sspo[c * 9 + pos] * cf[l];
    row_[(pos * 9 + m + 1) * 32 + c] = f2bf(v);     // [pos][j=m+1][c]
  }
  for (int t = tid; t < 288; t += 256) {            // j = 0 plane
    int c = t / 9, pos = t - c * 9;
    row_[(pos * 9) * 32 + c] = f2bf(sbo[t]);
  }
  __syncthreads();
  unsigned int* dst = (unsigned int*)(Wb + (size_t)o * 2592);
  const unsigned int* src = (const unsigned int*)row_;
  for (int i = tid; i < 1296; i += 256) dst[i] = src[i];
}

// ---------------------------------------------------------------------------
// K-loop, O32 x M32 per wave: 2 Wb frags share 2 a-frags -> 4 MFMAs/step.
// ---------------------------------------------------------------------------
template <int LO, int HI>
__device__ __forceinline__ void kloop2(const ushort_t* __restrict__ fb,
                                       const ushort_t* __restrict__ wp0,
                                       v4f& a00, v4f& a01, v4f& a10, v4f& a11) {
#pragma unroll
  for (int s = LO; s < HI; ++s) {
    const int di = s / 27;
    const int dj = (s / 9) % 3;
    const int kk = s % 9;
    const int fo = di * ROW_STRIDE + dj * CELL_STRIDE + kk * 32;
    v8s w0 = *(const v8s*)(wp0 + s * 32);
    v8s w1 = *(const v8s*)(wp0 + 16 * 2592 + s * 32);
    v8s a0 = *(const v8s*)(fb + fo);
    v8s a1 = *(const v8s*)(fb + fo + 16 * CELL_STRIDE);
    a00 = __builtin_amdgcn_mfma_f32_16x16x32_bf16(w0, a0, a00, 0, 0, 0);
    a01 = __builtin_amdgcn_mfma_f32_16x16x32_bf16(w0, a1, a01, 0, 0, 0);
    a10 = __builtin_amdgcn_mfma_f32_16x16x32_bf16(w1, a0, a10, 0, 0, 0);
    a11 = __builtin_amdgcn_mfma_f32_16x16x32_bf16(w1, a1, a11, 0, 0, 0);
  }
}

// ---------------------------------------------------------------------------
// Kernel 2: fused feat + conv + reduce.
// grid 256 = (b 8) x (oh 32); 1024 thr = 16 waves = (kq 8) x (og 2).
// ---------------------------------------------------------------------------
__global__ __launch_bounds__(1024, 4) void kan_fused(const float* __restrict__ x,
                                                     const ushort_t* __restrict__ Wb,
                                                     const float* __restrict__ bias,
                                                     float* __restrict__ out) {
  __shared__ __align__(16) unsigned char smem[SMEM_BYTES];
  ushort_t* feat = (ushort_t*)smem;                   // 60,384 B (Phase A/B)
  float*    xs   = (float*)(smem + XS_OFF);           // 3 x (32*33) fp32
  ushort_t* dump = (ushort_t*)(smem + DUMP_OFF);      // sink for invalid jj
  float*    red  = (float*)smem;                      // Phase C: 8 x 64 x 33 fp32

  const int tid = threadIdx.x;
  const int bx  = blockIdx.x;                // b*32 + oh
  const int oh  = bx & 31;
  const int b   = bx >> 5;

  // ---- pre-zero feat (b128 stores; barrier below covers the hazard) ----
  {
    v4i z = {0, 0, 0, 0};
    v4i* fz = (v4i*)feat;                    // 3,774 x 16B
#pragma unroll
    for (int k = 0; k < 4; ++k) {
      int i = tid + k * 1024;
      if (i < 3774) fz[i] = z;
    }
  }

  // ---- stage all 3 padded rows of x (h = oh-1..oh+1), then ONE barrier ----
#pragma unroll
  for (int r = 0; r < 3; ++r) {
    const int h = oh + r - 1;
    if (h >= 0 && h < 32) {
      int c = tid >> 5, w = tid & 31;        // 1024 floats: 32c x 32w
      xs[r * 1056 + c * 33 + w] = x[(((b * 32 + c) * 32 + h) * 32 + w)];
    }
  }
  __syncthreads();

  // ---- Phase A: feature strips, barrier-free across rows ----
#pragma unroll
  for (int r = 0; r < 3; ++r) {
    const int h = oh + r - 1;
    const bool hval = (h >= 0) && (h < 32);
    for (int idx = tid; idx < 1088; idx += 1024) {  // 34 cells x 32 c
      int c = idx & 31, cell = idx >> 5;
      int wi = cell - 1;
      float t = 0.0f;
      if (hval && wi >= 0 && wi < 32) t = xs[r * 1056 + c * 33 + wi];

      unsigned short f0 = f2bf(t / (1.0f + __expf(-t)));   // silu
      float u  = (t + 2.2f) * 2.5f;                        // spline param
      float fi = floorf(u);
      int   i  = (int)fi;
      float s  = u - fi;
      float s2 = s * s, s3 = s2 * s;
      float om = 1.0f - s;
      float w0 = om * om * om * (1.0f / 6.0f);
      float w1 = (4.0f - 6.0f * s2 + 3.0f * s3) * (1.0f / 6.0f);
      float w2 = (1.0f + 3.0f * s + 3.0f * s2 - 3.0f * s3) * (1.0f / 6.0f);
      float w3 = s3 * (1.0f / 6.0f);

      ushort_t* cb = feat + r * ROW_STRIDE + cell * CELL_STRIDE + c;
      cb[0] = f0;
      // only 4 bases are nonzero: basis jj = i-3+d gets w_d, d=0..3
#pragma unroll
      for (int d = 0; d < 4; ++d) {
        float wv_ = (d == 0) ? w0 : (d == 1) ? w1 : (d == 2) ? w2 : w3;
        int jj = i - 3 + d;
        ushort_t* p = ((unsigned)jj <= 7u) ? (cb + (jj + 1) * 32)
                                           : (dump + (tid & 63));
        *p = f2bf(wv_);
      }
    }
  }
  __syncthreads();

  // ---- Phase B: MFMA.  wave = (og: O32-group x2) x M32, kq = K-eighth ----
  const int wv   = tid >> 6;
  const int lane = tid & 63;
  const int row  = lane & 15;
  const int quad = lane >> 4;
  const int og   = wv & 1;
  const int kq   = wv >> 1;
  const int obase = og * 32;

  const ushort_t* fb  = feat + row * CELL_STRIDE + quad * 8;
  const ushort_t* wp0 = Wb + (size_t)(obase + row) * 2592 + quad * 8;

  v4f a00 = {0.f, 0.f, 0.f, 0.f};
  v4f a01 = a00, a10 = a00, a11 = a00;

  if      (kq == 0) kloop2< 0, 11>(fb, wp0, a00, a01, a10, a11);
  else if (kq == 1) kloop2<11, 21>(fb, wp0, a00, a01, a10, a11);
  else if (kq == 2) kloop2<21, 31>(fb, wp0, a00, a01, a10, a11);
  else if (kq == 3) kloop2<31, 41>(fb, wp0, a00, a01, a10, a11);
  else if (kq == 4) kloop2<41, 51>(fb, wp0, a00, a01, a10, a11);
  else if (kq == 5) kloop2<51, 61>(fb, wp0, a00, a01, a10, a11);
  else if (kq == 6) kloop2<61, 71>(fb, wp0, a00, a01, a10, a11);
  else              kloop2<71, 81>(fb, wp0, a00, a01, a10, a11);

  // ---- Phase C: all waves dump partials to LDS, fully-parallel reduce ----
  __syncthreads();                           // feat dead after this
  {
    // red[kq][o][pix], o-stride 33 (pad word), group stride 64*33 = 2112
    float* rp = red + kq * 2112 + (obase + quad * 4) * 33 + row;
#pragma unroll
    for (int r = 0; r < 4; ++r) {
      rp[r * 33]       = a00[r];             // o = obase+quad*4+r,    pix = row
      rp[r * 33 + 16]  = a01[r];             //                        pix = row+16
      rp[r * 33 + 528] = a10[r];             // o += 16 (wf1 group),   pix = row
      rp[r * 33 + 544] = a11[r];             //                        pix = row+16
    }
  }
  __syncthreads();
  {
    int o  = tid >> 4;                       // 0..63
    int p0 = (tid & 15) * 2;                 // 0,2,..,30
    float s0 = 0.f, s1 = 0.f;
#pragma unroll
    for (int g = 0; g < 8; ++g) {
      const float* rp = red + g * 2112 + o * 33 + p0;
      s0 += rp[0];
      s1 += rp[1];
    }
    float bv = bias[o];
    float2 v; v.x = s0 + bv; v.y = s1 + bv;
    *(float2*)(out + ((size_t)(b * 64 + o)) * 1024 + oh * 32 + p0) = v;
  }
}

// ---------------------------------------------------------------------------
extern "C" void kernel_launch(void* const* d_in, const int* in_sizes, int n_in,
                              void* d_out, int out_size, void* d_ws, size_t ws_size,
                              hipStream_t stream) {
  const float* x    = (const float*)d_in[0];
  const float* coef = (const float*)d_in[1];
  const float* sb   = (const float*)d_in[2];
  const float* ssp  = (const float*)d_in[3];
  const float* bias = (const float*)d_in[4];
  float* out = (float*)d_out;

  ushort_t* Wb = (ushort_t*)d_ws;            // 331,776 B

  hipLaunchKernelGGL(kan_prep, dim3(64), dim3(256), 0, stream, coef, sb, ssp, Wb);
  hipLaunchKernelGGL(kan_fused, dim3(256), dim3(1024), 0, stream, x, Wb, bias, out);
}